// Round 13
// baseline (91.628 us; speedup 1.0000x reference)
//
#include <hip/hip_runtime.h>
#include <hip/hip_bf16.h>

#define NB 8
#define NC 128
#define NH 48
#define NW 64
#define NS 3072  // NH*NW
#define EPSF 1e-6f

#define GLOBAL_AS __attribute__((address_space(1)))
#define LDS_AS __attribute__((address_space(3)))

typedef __bf16 bf16x8 __attribute__((ext_vector_type(8)));
typedef float f32x4 __attribute__((ext_vector_type(4)));

__device__ __forceinline__ unsigned short bf16_rtne(float f) {
  union { float f; unsigned u; } c;
  c.f = f;
  unsigned r = (c.u + 0x7fffu + ((c.u >> 16) & 1u)) >> 16;
  return (unsigned short)r;
}

// ---------------------------------------------------------------------------
// Transpose+convert (vectorized, unchanged from round 10):
// f32 [B][C][S] -> bf16 [B][S][C].
// ---------------------------------------------------------------------------
__global__ __launch_bounds__(256) void transpose_both(
    const float* __restrict__ x, const float* __restrict__ y,
    __hip_bfloat16* __restrict__ AT, __hip_bfloat16* __restrict__ BT) {
  __shared__ float tile[32 * 129];  // 16,512 B
  const int id = blockIdx.x;
  const int b = id & 7;             // XCD pin
  const int which = (id >> 3) & 1;
  const int f0 = (id >> 4) * 32;    // 0..95 strips
  const float* src = which ? y : x;
  __hip_bfloat16* dst = which ? BT : AT;
  const int t = threadIdx.x;

  {  // phase 1: float4 reads, scatter-transpose to LDS
    const int fl = (t & 7) * 4, cg0 = t >> 3;
    const float* sp = src + (size_t)b * NC * NS + f0 + fl;
#pragma unroll
    for (int i = 0; i < 4; ++i) {
      int cg = cg0 + i * 32;
      f32x4 v = *(const f32x4*)(sp + (size_t)cg * NS);
      tile[(fl + 0) * 129 + cg] = v[0];
      tile[(fl + 1) * 129 + cg] = v[1];
      tile[(fl + 2) * 129 + cg] = v[2];
      tile[(fl + 3) * 129 + cg] = v[3];
    }
  }
  __syncthreads();
  {  // phase 2: row reads, RTNE pack, ushort4 stores
    const int c4 = (t & 31) * 4, kl0 = t >> 5;
    unsigned short* dp = (unsigned short*)dst;
#pragma unroll
    for (int i = 0; i < 4; ++i) {
      int fl = kl0 + i * 8;
      int f = f0 + fl;
      int k = which ? f : ((f & 63) * NH + (f >> 6));  // x: k = v*H + u
      f32x4 v = *(const f32x4*)&tile[fl * 129 + c4];
      ushort4 u4;
      u4.x = bf16_rtne(v[0]);
      u4.y = bf16_rtne(v[1]);
      u4.z = bf16_rtne(v[2]);
      u4.w = bf16_rtne(v[3]);
      *(ushort4*)(dp + ((size_t)b * NS + k) * NC + c4) = u4;
    }
  }
}

// ---------------------------------------------------------------------------
// Staging: CPW 1-KB chunks per wave; linear LDS dest, inverse-swizzled global
// source (verified round-1 pattern). Read side uses granule g ^ (row&7).
// ---------------------------------------------------------------------------
template <int CPW>
__device__ __forceinline__ void stage_tile(const char* gsrc, char* ldst,
                                           int wid, int lane) {
  const int lr = lane >> 4, lg = lane & 15;
#pragma unroll
  for (int i = 0; i < CPW; ++i) {
    int c = wid * CPW + i;
    int row = c * 4 + lr;
    int g = lg ^ (row & 7);
    __builtin_amdgcn_global_load_lds(
        (const GLOBAL_AS unsigned*)(gsrc + row * 256 + g * 16),
        (LDS_AS unsigned*)(ldst + c * 1024), 16, 0, 0);
  }
}

// ---------------------------------------------------------------------------
// Pass 1 v3: 2 blocks/CU + true double-buffer with COUNTED vmcnt.
// Grid 1536 = 8 b x 24 nt x 8 mg; 256 threads (4 waves, 2x2 of 32x64).
// LDS = B 32K | A0 16K | A1 16K = 64 KB exactly -> 2 blocks/CU.
// Per iter over 6 A half-tiles (64 rows): issue stage(i+1), wait vmcnt(4)
// (stage(i) landed, stage(i+1) in flight), barrier, 32 MFMAs, barrier.
// part[mg][b][n] = sum over this block's 384 m-rows of relu(T)^2.
// ---------------------------------------------------------------------------
__global__ __launch_bounds__(256, 2) void corr_part_v3(
    const __hip_bfloat16* __restrict__ AT,
    const __hip_bfloat16* __restrict__ BT, float* __restrict__ part) {
  __shared__ char smem[65536];  // Bs 32K | A0 16K | A1 16K
  char* Bs = smem;
  const int id = blockIdx.x;  // 0..1535
  const int b = id & 7;       // XCD pin
  const int tl = id >> 3;     // 0..191
  const int nt = tl >> 3;     // 0..23
  const int mg = tl & 7;      // 0..7 (384 rows each)
  const int t = threadIdx.x;
  const int lane = t & 63, wid = t >> 6;
  const int wm = wid >> 1, wn = wid & 1;  // 2x2 -> 32 rows x 64 cols
  const int l15 = lane & 15, kg = lane >> 4;

  const char* Ab = (const char*)(AT + ((size_t)b * NS + mg * 384) * NC);
  const char* Bg = (const char*)(BT + ((size_t)b * NS + nt * 128) * NC);

  stage_tile<8>(Bg, Bs, wid, lane);        // 8 loads/lane
  stage_tile<4>(Ab, smem + 32768, wid, lane);  // half-tile 0 -> A0

  float cs[4] = {0.f, 0.f, 0.f, 0.f};
  const int rx = l15 & 7;
  int cur = 0;
#pragma unroll 1
  for (int i = 0; i < 6; ++i) {
    if (i < 5) {
      // prefetch next half-tile into the other buffer; DON'T wait for it
      stage_tile<4>(Ab + (size_t)(i + 1) * 16384,
                    smem + 32768 + ((cur ^ 1) << 14), wid, lane);
      asm volatile("s_waitcnt vmcnt(4)" ::: "memory");  // stage(i) + B landed
    } else {
      asm volatile("s_waitcnt vmcnt(0)" ::: "memory");
    }
    __builtin_amdgcn_sched_barrier(0);
    __builtin_amdgcn_s_barrier();  // all waves' loads for buf[cur] landed

    const char* As = smem + 32768 + (cur << 14);
    f32x4 acc[2][4] = {};
#pragma unroll
    for (int kk = 0; kk < 4; ++kk) {
      int g = (kk * 4 + kg) ^ rx;
      bf16x8 a[2], bb[4];
#pragma unroll
      for (int mi = 0; mi < 2; ++mi)
        a[mi] = *(const bf16x8*)(As + (wm * 32 + mi * 16 + l15) * 256 + g * 16);
#pragma unroll
      for (int ni = 0; ni < 4; ++ni)
        bb[ni] =
            *(const bf16x8*)(Bs + (wn * 64 + ni * 16 + l15) * 256 + g * 16);
#pragma unroll
      for (int mi = 0; mi < 2; ++mi)
#pragma unroll
        for (int ni = 0; ni < 4; ++ni)
          acc[mi][ni] = __builtin_amdgcn_mfma_f32_16x16x32_bf16(
              a[mi], bb[ni], acc[mi][ni], 0, 0, 0);
    }
#pragma unroll
    for (int ni = 0; ni < 4; ++ni)
#pragma unroll
      for (int mi = 0; mi < 2; ++mi)
#pragma unroll
        for (int r = 0; r < 4; ++r) {
          float v = fmaxf(acc[mi][ni][r], 0.f);
          cs[ni] += v * v;
        }
    __builtin_amdgcn_s_barrier();  // reads of buf[cur] done before restage
    cur ^= 1;
  }

#pragma unroll
  for (int ni = 0; ni < 4; ++ni) {
    cs[ni] += __shfl_xor(cs[ni], 16, 64);
    cs[ni] += __shfl_xor(cs[ni], 32, 64);
  }
  float* csum = (float*)smem;  // [2][128] (tiles fully consumed)
  __syncthreads();
  if (kg == 0) {
#pragma unroll
    for (int ni = 0; ni < 4; ++ni)
      csum[wm * 128 + wn * 64 + ni * 16 + l15] = cs[ni];
  }
  __syncthreads();
  if (t < 128) {
    float s = csum[t] + csum[128 + t];
    part[(size_t)mg * (NB * NS) + (size_t)b * NS + nt * 128 + t] = s;
  }
}

// ---------------------------------------------------------------------------
// Pass 2 (round-3 verified kernel): 128x128, repack-through-LDS epilogue,
// full-line dwordx4 nontemporal stores. Fused rn reads 8 partials.
// ---------------------------------------------------------------------------
__global__ __launch_bounds__(256, 2) void corr_out(
    const __hip_bfloat16* __restrict__ AT,
    const __hip_bfloat16* __restrict__ BT, const float* __restrict__ part_in,
    float* __restrict__ out) {
  __shared__ char smem[66560];  // A 32K | B 32K | rn 512 B
  float* rnc = (float*)(smem + 65536);
  const int id = blockIdx.x;
  const int b = id & 7;
  const int tl = id >> 3;
  const int mt = tl / 24, nt = tl - mt * 24;
  const int t = threadIdx.x;
  const int lane = t & 63, wid = t >> 6;
  const int wm = wid >> 1, wn = wid & 1;
  const int l15 = lane & 15, kg = lane >> 4;

  const char* Ag = (const char*)(AT + ((size_t)b * NS + mt * 128) * NC);
  const char* Bg = (const char*)(BT + ((size_t)b * NS + nt * 128) * NC);
  stage_tile<8>(Ag, smem, wid, lane);
  stage_tile<8>(Bg, smem + 32768, wid, lane);
  if (t < 128) {
    float s = 0.f;
#pragma unroll
    for (int q = 0; q < 8; ++q)
      s += part_in[(size_t)q * (NB * NS) + (size_t)b * NS + nt * 128 + t];
    rnc[t] = rsqrtf(s + EPSF);
  }
  __syncthreads();

  f32x4 acc[4][4] = {};
  const int rx = l15 & 7;
#pragma unroll
  for (int kk = 0; kk < 4; ++kk) {
    int g = (kk * 4 + kg) ^ rx;
    bf16x8 a[4], bb[4];
#pragma unroll
    for (int mi = 0; mi < 4; ++mi)
      a[mi] = *(const bf16x8*)(smem + (wm * 64 + mi * 16 + l15) * 256 + g * 16);
#pragma unroll
    for (int ni = 0; ni < 4; ++ni)
      bb[ni] = *(const bf16x8*)(smem + 32768 +
                                (wn * 64 + ni * 16 + l15) * 256 + g * 16);
#pragma unroll
    for (int mi = 0; mi < 4; ++mi)
#pragma unroll
      for (int ni = 0; ni < 4; ++ni)
        acc[mi][ni] = __builtin_amdgcn_mfma_f32_16x16x32_bf16(
            a[mi], bb[ni], acc[mi][ni], 0, 0, 0);
  }

  float rnv[4];
#pragma unroll
  for (int ni = 0; ni < 4; ++ni) rnv[ni] = rnc[wn * 64 + ni * 16 + l15];
  __syncthreads();  // tiles + rnc fully consumed

  float* tf = (float*)smem;  // [128][129]
#pragma unroll
  for (int mi = 0; mi < 4; ++mi)
#pragma unroll
    for (int ni = 0; ni < 4; ++ni)
#pragma unroll
      for (int r = 0; r < 4; ++r) {
        int row = wm * 64 + mi * 16 + kg * 4 + r;
        int col = wn * 64 + ni * 16 + l15;
        tf[row * 129 + col] = fmaxf(acc[mi][ni][r], 0.f) * rnv[ni];
      }
  __syncthreads();

  float* ob = out + (size_t)b * NS * NS + (size_t)(mt * 128) * NS + nt * 128;
  const int rsub = t >> 5, c4 = (t & 31) * 4;
#pragma unroll
  for (int it = 0; it < 16; ++it) {
    int row = it * 8 + rsub;
    f32x4 v = *(const f32x4*)&tf[row * 129 + c4];
    __builtin_nontemporal_store(v, (f32x4*)&ob[(size_t)row * NS + c4]);
  }
}

extern "C" void kernel_launch(void* const* d_in, const int* in_sizes, int n_in,
                              void* d_out, int out_size, void* d_ws,
                              size_t ws_size, hipStream_t stream) {
  const float* x = (const float*)d_in[0];
  const float* y = (const float*)d_in[1];
  float* out = (float*)d_out;
  char* ws = (char*)d_ws;

  const size_t AT_OFF = 0;           // 8*3072*128*2 = 6,291,456
  const size_t BT_OFF = 6291456;     // + 6,291,456
  const size_t PART_OFF = 12582912;  // 8*24576*4 = 786,432
  const size_t NEED = 13369344;
  if (ws_size < NEED) return;

  __hip_bfloat16* AT = (__hip_bfloat16*)(ws + AT_OFF);
  __hip_bfloat16* BT = (__hip_bfloat16*)(ws + BT_OFF);
  float* part = (float*)(ws + PART_OFF);

  transpose_both<<<dim3(1536), dim3(256), 0, stream>>>(x, y, AT, BT);
  corr_part_v3<<<dim3(1536), dim3(256), 0, stream>>>(AT, BT, part);
  corr_out<<<dim3(4608), dim3(256), 0, stream>>>(AT, BT, part, out);
}

// Round 14
// 90.153 us; speedup vs baseline: 1.0164x; 1.0164x over previous
//
#include <hip/hip_runtime.h>
#include <hip/hip_bf16.h>

#define NB 8
#define NC 128
#define NH 48
#define NW 64
#define NS 3072  // NH*NW
#define EPSF 1e-6f

#define GLOBAL_AS __attribute__((address_space(1)))
#define LDS_AS __attribute__((address_space(3)))

typedef __bf16 bf16x8 __attribute__((ext_vector_type(8)));
typedef float f32x4 __attribute__((ext_vector_type(4)));

__device__ __forceinline__ unsigned short bf16_rtne(float f) {
  union { float f; unsigned u; } c;
  c.f = f;
  unsigned r = (c.u + 0x7fffu + ((c.u >> 16) & 1u)) >> 16;
  return (unsigned short)r;
}

// ---------------------------------------------------------------------------
// Transpose+convert (vectorized, unchanged from round 10):
// f32 [B][C][S] -> bf16 [B][S][C].
// ---------------------------------------------------------------------------
__global__ __launch_bounds__(256) void transpose_both(
    const float* __restrict__ x, const float* __restrict__ y,
    __hip_bfloat16* __restrict__ AT, __hip_bfloat16* __restrict__ BT) {
  __shared__ float tile[32 * 129];  // 16,512 B
  const int id = blockIdx.x;
  const int b = id & 7;             // XCD pin
  const int which = (id >> 3) & 1;
  const int f0 = (id >> 4) * 32;    // 0..95 strips
  const float* src = which ? y : x;
  __hip_bfloat16* dst = which ? BT : AT;
  const int t = threadIdx.x;

  {  // phase 1: float4 reads, scatter-transpose to LDS
    const int fl = (t & 7) * 4, cg0 = t >> 3;
    const float* sp = src + (size_t)b * NC * NS + f0 + fl;
#pragma unroll
    for (int i = 0; i < 4; ++i) {
      int cg = cg0 + i * 32;
      f32x4 v = *(const f32x4*)(sp + (size_t)cg * NS);
      tile[(fl + 0) * 129 + cg] = v[0];
      tile[(fl + 1) * 129 + cg] = v[1];
      tile[(fl + 2) * 129 + cg] = v[2];
      tile[(fl + 3) * 129 + cg] = v[3];
    }
  }
  __syncthreads();
  {  // phase 2: row reads, RTNE pack, ushort4 stores
    const int c4 = (t & 31) * 4, kl0 = t >> 5;
    unsigned short* dp = (unsigned short*)dst;
#pragma unroll
    for (int i = 0; i < 4; ++i) {
      int fl = kl0 + i * 8;
      int f = f0 + fl;
      int k = which ? f : ((f & 63) * NH + (f >> 6));  // x: k = v*H + u
      f32x4 v = *(const f32x4*)&tile[fl * 129 + c4];
      ushort4 u4;
      u4.x = bf16_rtne(v[0]);
      u4.y = bf16_rtne(v[1]);
      u4.z = bf16_rtne(v[2]);
      u4.w = bf16_rtne(v[3]);
      *(ushort4*)(dp + ((size_t)b * NS + k) * NC + c4) = u4;
    }
  }
}

// ---------------------------------------------------------------------------
// Staging: CPW 1-KB chunks per wave; linear LDS dest, inverse-swizzled global
// source (verified round-1 pattern). Read side uses granule g ^ (row&7).
// ---------------------------------------------------------------------------
template <int CPW>
__device__ __forceinline__ void stage_tile(const char* gsrc, char* ldst,
                                           int wid, int lane) {
  const int lr = lane >> 4, lg = lane & 15;
#pragma unroll
  for (int i = 0; i < CPW; ++i) {
    int c = wid * CPW + i;
    int row = c * 4 + lr;
    int g = lg ^ (row & 7);
    __builtin_amdgcn_global_load_lds(
        (const GLOBAL_AS unsigned*)(gsrc + row * 256 + g * 16),
        (LDS_AS unsigned*)(ldst + c * 1024), 16, 0, 0);
  }
}

// ---------------------------------------------------------------------------
// Pass 1 (round-12 verified v2, best known): 2 blocks/CU persistent.
// Grid 1536 = 8 b x 24 nt x 8 mg; 256 threads (4 waves, 2x2 of 64x64).
// part[mg][b][n] = sum over this block's 384 m-rows of relu(T)^2.
// ---------------------------------------------------------------------------
__global__ __launch_bounds__(256, 2) void corr_part_v2(
    const __hip_bfloat16* __restrict__ AT,
    const __hip_bfloat16* __restrict__ BT, float* __restrict__ part) {
  __shared__ char smem[65536];  // As 32K | Bs 32K
  char* As = smem;
  char* Bs = smem + 32768;
  const int id = blockIdx.x;  // 0..1535
  const int b = id & 7;       // XCD pin
  const int tl = id >> 3;     // 0..191
  const int nt = tl >> 3;     // 0..23
  const int mg = tl & 7;      // 0..7 (3 tiles of 128 rows each)
  const int t = threadIdx.x;
  const int lane = t & 63, wid = t >> 6;
  const int wm = wid >> 1, wn = wid & 1;
  const int l15 = lane & 15, kg = lane >> 4;

  const char* Ab = (const char*)(AT + ((size_t)b * NS + mg * 384) * NC);
  const char* Bg = (const char*)(BT + ((size_t)b * NS + nt * 128) * NC);

  stage_tile<8>(Bg, Bs, wid, lane);

  float cs[4] = {0.f, 0.f, 0.f, 0.f};
  const int rx = l15 & 7;
#pragma unroll 1
  for (int i = 0; i < 3; ++i) {
    stage_tile<8>(Ab + (size_t)i * 32768, As, wid, lane);
    asm volatile("s_waitcnt vmcnt(0)" ::: "memory");
    __builtin_amdgcn_sched_barrier(0);
    __builtin_amdgcn_s_barrier();

    f32x4 acc[4][4] = {};
#pragma unroll
    for (int kk = 0; kk < 4; ++kk) {
      int g = (kk * 4 + kg) ^ rx;
      bf16x8 a[4], bb[4];
#pragma unroll
      for (int mi = 0; mi < 4; ++mi)
        a[mi] = *(const bf16x8*)(As + (wm * 64 + mi * 16 + l15) * 256 + g * 16);
#pragma unroll
      for (int ni = 0; ni < 4; ++ni)
        bb[ni] =
            *(const bf16x8*)(Bs + (wn * 64 + ni * 16 + l15) * 256 + g * 16);
#pragma unroll
      for (int mi = 0; mi < 4; ++mi)
#pragma unroll
        for (int ni = 0; ni < 4; ++ni)
          acc[mi][ni] = __builtin_amdgcn_mfma_f32_16x16x32_bf16(
              a[mi], bb[ni], acc[mi][ni], 0, 0, 0);
    }
#pragma unroll
    for (int ni = 0; ni < 4; ++ni)
#pragma unroll
      for (int mi = 0; mi < 4; ++mi)
#pragma unroll
        for (int r = 0; r < 4; ++r) {
          float v = fmaxf(acc[mi][ni][r], 0.f);
          cs[ni] += v * v;
        }
    __builtin_amdgcn_s_barrier();  // all waves done reading As before restage
  }

#pragma unroll
  for (int ni = 0; ni < 4; ++ni) {
    cs[ni] += __shfl_xor(cs[ni], 16, 64);
    cs[ni] += __shfl_xor(cs[ni], 32, 64);
  }
  float* csum = (float*)smem;  // [2][128]
  if (kg == 0) {
#pragma unroll
    for (int ni = 0; ni < 4; ++ni)
      csum[wm * 128 + wn * 64 + ni * 16 + l15] = cs[ni];
  }
  __syncthreads();
  if (t < 128) {
    float s = csum[t] + csum[128 + t];
    part[(size_t)mg * (NB * NS) + (size_t)b * NS + nt * 128 + t] = s;
  }
}

// ---------------------------------------------------------------------------
// Pass 2 v2: wave-private quadrant epilogue. 128x128 tile, 4 waves.
// After MFMA + ONE barrier (A/B dead), each wave independently repacks its
// own 64x64 quadrant into a private f32 [64][68] region (272 B row stride:
// 16 B-aligned, 2-way-max bank aliasing = free) and nt-stores it as 16
// instructions x 256 B segments (2 full 128 B lines each). No block-wide tf
// dependency, no post-repack barrier: stores start earlier and stagger.
// LDS = max(A+B 64K, 4 x 17,408 quadrants) + rn 512 = 70,144 -> 2 blocks/CU.
// ---------------------------------------------------------------------------
__global__ __launch_bounds__(256, 2) void corr_out(
    const __hip_bfloat16* __restrict__ AT,
    const __hip_bfloat16* __restrict__ BT, const float* __restrict__ part_in,
    float* __restrict__ out) {
  __shared__ char smem[70144];
  float* rnc = (float*)(smem + 69632);
  const int id = blockIdx.x;
  const int b = id & 7;
  const int tl = id >> 3;
  const int mt = tl / 24, nt = tl - mt * 24;
  const int t = threadIdx.x;
  const int lane = t & 63, wid = t >> 6;
  const int wm = wid >> 1, wn = wid & 1;
  const int l15 = lane & 15, kg = lane >> 4;

  const char* Ag = (const char*)(AT + ((size_t)b * NS + mt * 128) * NC);
  const char* Bg = (const char*)(BT + ((size_t)b * NS + nt * 128) * NC);
  stage_tile<8>(Ag, smem, wid, lane);
  stage_tile<8>(Bg, smem + 32768, wid, lane);
  if (t < 128) {
    float s = 0.f;
#pragma unroll
    for (int q = 0; q < 8; ++q)
      s += part_in[(size_t)q * (NB * NS) + (size_t)b * NS + nt * 128 + t];
    rnc[t] = rsqrtf(s + EPSF);
  }
  __syncthreads();

  f32x4 acc[4][4] = {};
  const int rx = l15 & 7;
#pragma unroll
  for (int kk = 0; kk < 4; ++kk) {
    int g = (kk * 4 + kg) ^ rx;
    bf16x8 a[4], bb[4];
#pragma unroll
    for (int mi = 0; mi < 4; ++mi)
      a[mi] = *(const bf16x8*)(smem + (wm * 64 + mi * 16 + l15) * 256 + g * 16);
#pragma unroll
    for (int ni = 0; ni < 4; ++ni)
      bb[ni] = *(const bf16x8*)(smem + 32768 +
                                (wn * 64 + ni * 16 + l15) * 256 + g * 16);
#pragma unroll
    for (int mi = 0; mi < 4; ++mi)
#pragma unroll
      for (int ni = 0; ni < 4; ++ni)
        acc[mi][ni] = __builtin_amdgcn_mfma_f32_16x16x32_bf16(
            a[mi], bb[ni], acc[mi][ni], 0, 0, 0);
  }

  float rnv[4];
#pragma unroll
  for (int ni = 0; ni < 4; ++ni) rnv[ni] = rnc[wn * 64 + ni * 16 + l15];
  __syncthreads();  // A/B tiles consumed by ALL waves; quadrants may overwrite

  // wave-private repack: 64x64 quadrant -> f32 [64][68]
  float* tfw = (float*)(smem + wid * 17408);
#pragma unroll
  for (int mi = 0; mi < 4; ++mi)
#pragma unroll
    for (int ni = 0; ni < 4; ++ni)
#pragma unroll
      for (int r = 0; r < 4; ++r) {
        int lr = mi * 16 + kg * 4 + r;   // 0..63 local row
        int lc = ni * 16 + l15;          // 0..63 local col
        tfw[lr * 68 + lc] = fmaxf(acc[mi][ni][r], 0.f) * rnv[ni];
      }

  // wave-private stores: row = R0 + 4*kg, 16 lanes x 16 B = 256 B contiguous
  float* ob = out + (size_t)b * NS * NS +
              (size_t)(mt * 128 + wm * 64) * NS + nt * 128 + wn * 64;
#pragma unroll
  for (int g2 = 0; g2 < 4; ++g2)
#pragma unroll
    for (int it = 0; it < 4; ++it) {
      int row = g2 * 16 + it + 4 * kg;  // (row>>2)&3 distinct across kg
      f32x4 v = *(const f32x4*)&tfw[row * 68 + l15 * 4];
      __builtin_nontemporal_store(v, (f32x4*)&ob[(size_t)row * NS + l15 * 4]);
    }
}

extern "C" void kernel_launch(void* const* d_in, const int* in_sizes, int n_in,
                              void* d_out, int out_size, void* d_ws,
                              size_t ws_size, hipStream_t stream) {
  const float* x = (const float*)d_in[0];
  const float* y = (const float*)d_in[1];
  float* out = (float*)d_out;
  char* ws = (char*)d_ws;

  const size_t AT_OFF = 0;           // 8*3072*128*2 = 6,291,456
  const size_t BT_OFF = 6291456;     // + 6,291,456
  const size_t PART_OFF = 12582912;  // 8*24576*4 = 786,432
  const size_t NEED = 13369344;
  if (ws_size < NEED) return;

  __hip_bfloat16* AT = (__hip_bfloat16*)(ws + AT_OFF);
  __hip_bfloat16* BT = (__hip_bfloat16*)(ws + BT_OFF);
  float* part = (float*)(ws + PART_OFF);

  transpose_both<<<dim3(1536), dim3(256), 0, stream>>>(x, y, AT, BT);
  corr_part_v2<<<dim3(1536), dim3(256), 0, stream>>>(AT, BT, part);
  corr_out<<<dim3(4608), dim3(256), 0, stream>>>(AT, BT, part, out);
}